// Round 5
// baseline (3609.867 us; speedup 1.0000x reference)
//
#include <hip/hip_runtime.h>

#define T_TOT 1024
#define BB 64
#define DD 128
#define HH 256
#define GG 1024
#define OO 64
#define LN_EPS 1e-3f
#define NBR 45   // B-fragment tiles per wave kept in registers (180 VGPR/AGPR)
#define NBL 19   // B-fragment tiles per wave kept in LDS (NBR+NBL = 64)

typedef unsigned int u32;
typedef _Float16 h2 __attribute__((ext_vector_type(2)));
typedef _Float16 f16x8 __attribute__((ext_vector_type(8)));
typedef float f32x4 __attribute__((ext_vector_type(4)));

__device__ __forceinline__ float fdot2(u32 a, u32 b, float c) {
  return __builtin_amdgcn_fdot2(__builtin_bit_cast(h2, a), __builtin_bit_cast(h2, b), c, false);
}
__device__ __forceinline__ u32 pkf16(float lo, float hi) {
  h2 v = { (_Float16)lo, (_Float16)hi };
  return __builtin_bit_cast(u32, v);
}
__device__ __forceinline__ float fast_sigmoid(float x) { return 1.0f / (1.0f + __expf(-x)); }
__device__ __forceinline__ float fast_tanh(float x) { return 2.0f / (1.0f + __expf(-2.0f * x)) - 1.0f; }

// ---- prep: pack Wh (4H x H) into per-wave MFMA B-fragments.
// Tile (w, t, n): B[k][col] slice with col = w*128 + n*16 + (lane&15),
// k = t*32 + (lane>>4)*8 + j  (j = 0..7).  bfragG[(w*64 + t*8+n)*64 + lane].
__global__ void prep_bfrag(const float* __restrict__ Wh, uint4* __restrict__ bfragG) {
  int id = blockIdx.x * 256 + threadIdx.x;     // 32768 slots
  int lane = id & 63, tile = (id >> 6) & 63, w = id >> 12;
  int t = tile >> 3, n = tile & 7;
  int col = w * 128 + n * 16 + (lane & 15);    // gate index g
  int k0 = t * 32 + (lane >> 4) * 8;
  const float* p = Wh + (size_t)col * HH + k0; // Wh[g][k0..k0+7], contiguous
  uint4 o;
  o.x = pkf16(p[0], p[1]); o.y = pkf16(p[2], p[3]);
  o.z = pkf16(p[4], p[5]); o.w = pkf16(p[6], p[7]);
  bfragG[id] = o;
}

__global__ void prep_wi(const float* __restrict__ Wi, uint4* __restrict__ wip4) {
  int id = blockIdx.x * 256 + threadIdx.x;     // 16384
  int kp4 = id >> 10, g = id & 1023;
  const float* p = Wi + (size_t)g * DD + kp4 * 8;
  uint4 o;
  o.x = pkf16(p[0], p[1]); o.y = pkf16(p[2], p[3]);
  o.z = pkf16(p[4], p[5]); o.w = pkf16(p[6], p[7]);
  wip4[id] = o;
}

// ---------------- xproj GEMM: writes xphf in fragment order:
// row ml, offset (g>>7)*128 + (g&15)*8 + ((g>>4)&7)  -> lane l4 of wave w
// reads its 8 n-values as one contiguous f16x8.
__global__ __launch_bounds__(256) void xproj_gemm(
    const float* __restrict__ x, const uint4* __restrict__ wip4,
    const float* __restrict__ bi, const float* __restrict__ bh,
    _Float16* __restrict__ xph, int m0) {
  __shared__ _Float16 xl[16][128];
  const int tid = threadIdx.x;
  const int mt = blockIdx.x, gt = blockIdx.y;
  const int g = gt * 256 + tid;
  const int woff = ((g >> 7) << 7) | ((g & 15) << 3) | ((g >> 4) & 7);
#pragma unroll
  for (int i = 0; i < 8; ++i) {
    int idx = i * 256 + tid;          // 0..2047
    int p = idx >> 7, d = idx & 127;
    int m = m0 + mt * 16 + p;         // global m = t*64+b
    xl[p][d] = (_Float16)x[(size_t)(m & 63) * (T_TOT * DD) + (size_t)(m >> 6) * DD + d];
  }
  __syncthreads();
  float acc[16];
#pragma unroll
  for (int p = 0; p < 16; ++p) acc[p] = 0.f;
#pragma unroll
  for (int kp4 = 0; kp4 < 16; ++kp4) {
    uint4 w = wip4[kp4 * GG + g];
#pragma unroll
    for (int p = 0; p < 16; ++p) {
      uint4 hv = *(const uint4*)(&xl[p][kp4 * 8]);   // uniform addr -> broadcast
      acc[p] = fdot2(w.x, hv.x, acc[p]);
      acc[p] = fdot2(w.y, hv.y, acc[p]);
      acc[p] = fdot2(w.z, hv.z, acc[p]);
      acc[p] = fdot2(w.w, hv.w, acc[p]);
    }
  }
  float bsum = bi[g] + bh[g];
#pragma unroll
  for (int p = 0; p < 16; ++p) {
    int ml = mt * 16 + p;
    xph[(size_t)ml * GG + woff] = (_Float16)(acc[p] + bsum);
  }
}

// ---------------- scan v5 (MFMA): one block per batch, 512 threads / 8 waves.
// Wave w owns gates [w*128, w*128+128): 8 N-tiles x 8 K-tiles of
// v_mfma_f32_16x16x32_f16 with M=1 (A row 0 = hx, rows 1-15 zero).
// B-fragments: NBR tiles in regs (MFMA reads VGPR or AGPR), NBL in LDS.
// D row 0 lives in lanes 0-15, reg 0 (verified C/D layout).
__global__ __attribute__((amdgpu_flat_work_group_size(512, 512), amdgpu_waves_per_eu(2, 2)))
void lstm_scan(
    const uint4* __restrict__ bfragG, const _Float16* __restrict__ xphf,
    const float* __restrict__ lna_g, const float* __restrict__ lna_b,
    const float* __restrict__ ln_g, const float* __restrict__ ln_b,
    _Float16* __restrict__ hs16,
    _Float16* __restrict__ hxst, float* __restrict__ cxst,
    int t0, int ct) {
  extern __shared__ char smem[];
  f16x8* wl = (f16x8*)smem;                         // [8][NBL][64] f16x8 = 155648 B
  _Float16* hx16 = (_Float16*)(smem + 155648);      // 256 f16 = 512 B
  float* red  = (float*)(smem + 156160);            // 16 floats
  float* red2 = (float*)(smem + 156224);            // 8 floats
  float* gact = (float*)(smem + 156256);            // 1024 floats -> end 160352

  const int tid = threadIdx.x, b = blockIdx.x;
  const int lane = tid & 63, wid = tid >> 6, q = wid >> 1;
  const int l4 = lane & 15;

  // load B-fragments: 45 tiles -> regs, 19 tiles -> LDS
  const uint4* bw = bfragG + wid * 4096;
  f16x8 breg[NBR];
#pragma unroll
  for (int i = 0; i < NBR; ++i) breg[i] = __builtin_bit_cast(f16x8, bw[i * 64 + lane]);
#pragma unroll
  for (int i = NBR; i < 64; ++i)
    wl[(wid * NBL + (i - NBR)) * 64 + lane] = __builtin_bit_cast(f16x8, bw[i * 64 + lane]);

  // layer_norm_all affine coeffs, packed f16 (8 gates per lane: n = 0..7)
  u32 lgp[4], lbp[4];
#pragma unroll
  for (int k = 0; k < 4; ++k) {
    int g0 = wid * 128 + (2 * k) * 16 + l4;
    lgp[k] = pkf16(lna_g[g0], lna_g[g0 + 16]);
    lbp[k] = pkf16(lna_b[g0], lna_b[g0 + 16]);
  }
  float lng = 0.f, lnb = 0.f, cx = 0.f;
  if (tid < HH) {
    lng = ln_g[tid]; lnb = ln_b[tid];
    if (t0 == 0) {
      hx16[tid] = (_Float16)0.f;
    } else {
      hx16[tid] = hxst[b * HH + tid]; cx = cxst[b * HH + tid];
    }
  }
  __syncthreads();

  const _Float16* xrow = xphf + (size_t)b * GG + wid * 128 + l4 * 8;
  _Float16* hsp = hs16 + (size_t)b * HH + (tid & 255);

  f16x8 xp = *(const f16x8*)xrow;    // 8 n-values for this lane's gates
  for (int tl = 0; tl < ct; ++tl) {
    f32x4 acc[8];
#pragma unroll
    for (int n = 0; n < 8; ++n) acc[n] = (f32x4){0.f, 0.f, 0.f, 0.f};
#pragma unroll
    for (int t = 0; t < 8; ++t) {
      // A-frag for K-tile t: lanes with l4==0 carry hx[t*32 + (lane>>4)*8 + j]
      uint4 hv = *(const uint4*)(hx16 + t * 32 + ((lane >> 4) << 3));  // broadcast
      uint4 az;
      az.x = (l4 == 0) ? hv.x : 0u;
      az.y = (l4 == 0) ? hv.y : 0u;
      az.z = (l4 == 0) ? hv.z : 0u;
      az.w = (l4 == 0) ? hv.w : 0u;
      f16x8 afr = __builtin_bit_cast(f16x8, az);
#pragma unroll
      for (int n = 0; n < 8; ++n) {
        const int idx = t * 8 + n;
        f16x8 bfr;
        if (idx < NBR) bfr = breg[idx];
        else           bfr = wl[(wid * NBL + (idx - NBR)) * 64 + lane];
        acc[n] = __builtin_amdgcn_mfma_f32_16x16x32_f16(afr, bfr, acc[n], 0, 0, 0);
      }
    }
    // gates (lanes 0-15 hold row 0 in acc[n][0]); lanes>=16 compute zeros+junk xp, isolated below
    float g8[8];
#pragma unroll
    for (int n = 0; n < 8; ++n) g8[n] = acc[n][0] + (float)xp[n];
    if (tl + 1 < ct) xp = *(const f16x8*)(xrow + (size_t)(tl + 1) * (BB * GG));

    // gate-block LN over 256 gates = waves {2q, 2q+1}; reduce lanes 0-15 only
    float s = 0.f, ss = 0.f;
#pragma unroll
    for (int n = 0; n < 8; ++n) { s += g8[n]; ss += g8[n] * g8[n]; }
#pragma unroll
    for (int m = 1; m <= 8; m <<= 1) {
      s += __shfl_xor(s, m, 64);
      ss += __shfl_xor(ss, m, 64);
    }
    if (lane == 0) { red[wid] = s; red[8 + wid] = ss; }
    __syncthreads();                                  // B1
    float S  = red[2 * q] + red[2 * q + 1];
    float SS = red[8 + 2 * q] + red[8 + 2 * q + 1];
    float mean = S * (1.f / HH);
    float var = SS * (1.f / HH) - mean * mean;
    float rstd = rsqrtf(var + LN_EPS);
    if (lane < 16) {
#pragma unroll
      for (int n = 0; n < 8; ++n) {
        h2 lgv = __builtin_bit_cast(h2, lgp[n >> 1]);
        h2 lbv = __builtin_bit_cast(h2, lbp[n >> 1]);
        float gn = (g8[n] - mean) * rstd * (float)lgv[n & 1] + (float)lbv[n & 1];
        float av = (q == 2) ? fast_tanh(gn) : fast_sigmoid(gn);   // wave-uniform branch
        gact[wid * 128 + n * 16 + lane] = av;
      }
    }
    __syncthreads();                                  // B2

    float cy = 0.f;
    if (tid < HH) {
      int h = tid;
      cy = gact[HH + h] * cx + gact[h] * gact[2 * HH + h];
      cx = cy;
      float s2 = cy, ss2 = cy * cy;
#pragma unroll
      for (int m = 1; m <= 32; m <<= 1) {
        s2 += __shfl_xor(s2, m, 64);
        ss2 += __shfl_xor(ss2, m, 64);
      }
      if (lane == 0) { red2[wid] = s2; red2[4 + wid] = ss2; }
    }
    __syncthreads();                                  // B3
    if (tid < HH) {
      int h = tid;
      float S2  = red2[0] + red2[1] + red2[2] + red2[3];
      float SS2 = red2[4] + red2[5] + red2[6] + red2[7];
      float mc = S2 * (1.f / HH);
      float vc = SS2 * (1.f / HH) - mc * mc;
      float cyn = (cy - mc) * rsqrtf(vc + LN_EPS) * lng + lnb;
      float hy = gact[3 * HH + h] * fast_tanh(cyn);
      hx16[h] = (_Float16)hy;
      hsp[(size_t)(t0 + tl) * (BB * HH)] = (_Float16)hy;
    }
    __syncthreads();                                  // B4
  }
  if (tid < HH) { hxst[b * HH + tid] = hx16[tid]; cxst[b * HH + tid] = cx; }
}

// ---------------- out GEMM: out[b][t][o] = relu(sum_h hs[t][b][h]*Wf[o][h] + bf[o])
__global__ __launch_bounds__(256) void out_gemm(
    const _Float16* __restrict__ hs16, const float* __restrict__ Wf,
    const float* __restrict__ bf, float* __restrict__ out) {
  __shared__ u32 wfl[128][64];    // pairs [kp][o], 32KB
  __shared__ u32 hsl[16][132];    // pairs [p][kp], padded
  const int tid = threadIdx.x;
  const int mbase = blockIdx.x * 16;
#pragma unroll
  for (int i = 0; i < 32; ++i) {  // 8192 pairs of Wf
    int idx = i * 256 + tid;
    int kp = idx >> 6, o = idx & 63;
    wfl[kp][o] = pkf16(Wf[o * HH + kp * 2], Wf[o * HH + kp * 2 + 1]);
  }
#pragma unroll
  for (int i = 0; i < 8; ++i) {   // 2048 pairs of hs
    int idx = i * 256 + tid;
    int p = idx >> 7, kp = idx & 127;
    hsl[p][kp] = *(const u32*)(hs16 + (size_t)(mbase + p) * HH + kp * 2);
  }
  __syncthreads();
  const int o = tid & 63, mi = tid >> 6;
  float bfo = bf[o];
#pragma unroll
  for (int mm = mi; mm < 16; mm += 4) {
    float a0 = bfo, a1 = 0.f, a2 = 0.f, a3 = 0.f;
#pragma unroll
    for (int kp = 0; kp < 128; kp += 4) {
      a0 = fdot2(wfl[kp + 0][o], hsl[mm][kp + 0], a0);
      a1 = fdot2(wfl[kp + 1][o], hsl[mm][kp + 1], a1);
      a2 = fdot2(wfl[kp + 2][o], hsl[mm][kp + 2], a2);
      a3 = fdot2(wfl[kp + 3][o], hsl[mm][kp + 3], a3);
    }
    float r = (a0 + a1) + (a2 + a3);
    int m = mbase + mm;
    out[(size_t)(m & 63) * (T_TOT * OO) + (size_t)(m >> 6) * OO + o] = fmaxf(r, 0.f);
  }
}

extern "C" void kernel_launch(void* const* d_in, const int* in_sizes, int n_in,
                              void* d_out, int out_size, void* d_ws, size_t ws_size,
                              hipStream_t stream) {
  if (n_in < 11) return;
  const float* x    = (const float*)d_in[0];
  const float* Wi   = (const float*)d_in[1];
  const float* bi   = (const float*)d_in[2];
  const float* Wh   = (const float*)d_in[3];
  const float* bh   = (const float*)d_in[4];
  const float* lnag = (const float*)d_in[5];
  const float* lnab = (const float*)d_in[6];
  const float* lng  = (const float*)d_in[7];
  const float* lnb  = (const float*)d_in[8];
  const float* Wf   = (const float*)d_in[9];
  const float* bf   = (const float*)d_in[10];
  float* out = (float*)d_out;

  char* ws = (char*)d_ws;
  uint4* bfragG = (uint4*)ws;                                // 512 KB
  uint4* wip4 = (uint4*)(ws + (512 << 10));                  // 256 KB
  _Float16* hs16 = (_Float16*)(ws + (1 << 20));              // 32 MB
  _Float16* hxst = (_Float16*)(ws + (1 << 20) + (32 << 20)); // 32 KB
  float* cxst = (float*)(ws + (1 << 20) + (32 << 20) + (64 << 10)); // 64 KB
  const size_t xph_off = (size_t)35 << 20;
  _Float16* xph = (_Float16*)(ws + xph_off);

  size_t avail = ws_size > xph_off ? ws_size - xph_off : 0;
  int ct = T_TOT;
  while (ct > 1 && (size_t)ct * (BB * GG * 2) > avail) ct >>= 1;

  const int scan_smem = 160352;   // 155648 wl + 512 hx + 64 red + 32 red2 + 4096 gact
  (void)hipFuncSetAttribute(reinterpret_cast<const void*>(lstm_scan),
                            hipFuncAttributeMaxDynamicSharedMemorySize, scan_smem);

  prep_bfrag<<<128, 256, 0, stream>>>(Wh, bfragG);
  prep_wi<<<64, 256, 0, stream>>>(Wi, wip4);
  for (int t0 = 0; t0 < T_TOT; t0 += ct) {
    xproj_gemm<<<dim3((ct * BB) / 16, 4), 256, 0, stream>>>(x, wip4, bi, bh, xph, t0 * BB);
    lstm_scan<<<BB, 512, scan_smem, stream>>>(bfragG, xph, lnag, lnab, lng, lnb,
                                              hs16, hxst, cxst, t0, ct);
  }
  out_gemm<<<(T_TOT * BB) / 16, 256, 0, stream>>>(hs16, Wf, bf, out);
}

// Round 6
// 2912.478 us; speedup vs baseline: 1.2394x; 1.2394x over previous
//
#include <hip/hip_runtime.h>

#define T_TOT 1024
#define BB 64
#define DD 128
#define HH 256
#define GG 1024
#define OO 64
#define LN_EPS 1e-3f
#define NV 25   // uint4 weight chunks per gate in regs (200 dwords for 2 gates; overflow -> AGPR)
#define NL 7    // uint4 weight chunks per gate in LDS (NV+NL=32); wl = 114KB

typedef unsigned int u32;
typedef _Float16 h2 __attribute__((ext_vector_type(2)));

__device__ __forceinline__ float fdot2(u32 a, u32 b, float c) {
  return __builtin_amdgcn_fdot2(__builtin_bit_cast(h2, a), __builtin_bit_cast(h2, b), c, false);
}
__device__ __forceinline__ u32 pkf16(float lo, float hi) {
  h2 v = { (_Float16)lo, (_Float16)hi };
  return __builtin_bit_cast(u32, v);
}
__device__ __forceinline__ float fast_sigmoid(float x) { return 1.0f / (1.0f + __expf(-x)); }
__device__ __forceinline__ float fast_tanh(float x) { return 2.0f / (1.0f + __expf(-2.0f * x)) - 1.0f; }

// ---------------- prep: pack Wh (4H x H) into f16 pairs, chunked by 8 along H ----
__global__ void prep_wh(const float* __restrict__ Wh, uint4* __restrict__ whp4) {
  int id = blockIdx.x * 256 + threadIdx.x;     // 32768
  int kb = id >> 10, g = id & 1023;
  const float* p = Wh + (size_t)g * HH + kb * 8;
  uint4 o;
  o.x = pkf16(p[0], p[1]); o.y = pkf16(p[2], p[3]);
  o.z = pkf16(p[4], p[5]); o.w = pkf16(p[6], p[7]);
  whp4[id] = o;
}

__global__ void prep_wi(const float* __restrict__ Wi, uint4* __restrict__ wip4) {
  int id = blockIdx.x * 256 + threadIdx.x;     // 16384
  int kp4 = id >> 10, g = id & 1023;
  const float* p = Wi + (size_t)g * DD + kp4 * 8;
  uint4 o;
  o.x = pkf16(p[0], p[1]); o.y = pkf16(p[2], p[3]);
  o.z = pkf16(p[4], p[5]); o.w = pkf16(p[6], p[7]);
  wip4[id] = o;
}

// ---------------- xproj GEMM: xph[ml][g] = sum_d x[b][t][d]*Wi[g][d] + bi[g]+bh[g]
__global__ __launch_bounds__(256) void xproj_gemm(
    const float* __restrict__ x, const uint4* __restrict__ wip4,
    const float* __restrict__ bi, const float* __restrict__ bh,
    _Float16* __restrict__ xph, int m0) {
  __shared__ _Float16 xl[16][128];
  const int tid = threadIdx.x;
  const int mt = blockIdx.x, gt = blockIdx.y;
  const int g = gt * 256 + tid;
#pragma unroll
  for (int i = 0; i < 8; ++i) {
    int idx = i * 256 + tid;          // 0..2047
    int p = idx >> 7, d = idx & 127;
    int m = m0 + mt * 16 + p;         // global m = t*64+b
    xl[p][d] = (_Float16)x[(size_t)(m & 63) * (T_TOT * DD) + (size_t)(m >> 6) * DD + d];
  }
  __syncthreads();
  float acc[16];
#pragma unroll
  for (int p = 0; p < 16; ++p) acc[p] = 0.f;
#pragma unroll
  for (int kp4 = 0; kp4 < 16; ++kp4) {
    uint4 w = wip4[kp4 * GG + g];
#pragma unroll
    for (int p = 0; p < 16; ++p) {
      uint4 hv = *(const uint4*)(&xl[p][kp4 * 8]);   // uniform addr -> broadcast
      acc[p] = fdot2(w.x, hv.x, acc[p]);
      acc[p] = fdot2(w.y, hv.y, acc[p]);
      acc[p] = fdot2(w.z, hv.z, acc[p]);
      acc[p] = fdot2(w.w, hv.w, acc[p]);
    }
  }
  float bsum = bi[g] + bh[g];
#pragma unroll
  for (int p = 0; p < 16; ++p) {
    int ml = mt * 16 + p;
    xph[(size_t)ml * GG + g] = (_Float16)(acc[p] + bsum);
  }
}

// ---------------- scan v6: 512 threads, 2 gates/thread. hx distribution via
// v_readlane (VALU) instead of LDS b128 broadcasts: lane l holds hx[4l..4l+3]
// in a uint2; each weight chunk's 4 hx dwords come from readlane at
// compile-time lane indices. Removes ~3000cy/step of LDS-pipe broadcasts.
__global__ __attribute__((amdgpu_flat_work_group_size(512, 512), amdgpu_waves_per_eu(2, 2)))
void lstm_scan(
    const uint4* __restrict__ whp4, const _Float16* __restrict__ xphf,
    const float* __restrict__ lna_g, const float* __restrict__ lna_b,
    const float* __restrict__ ln_g, const float* __restrict__ ln_b,
    _Float16* __restrict__ hs16,
    _Float16* __restrict__ hxst, float* __restrict__ cxst,
    int t0, int ct) {
  extern __shared__ char smem[];
  uint4* wl = (uint4*)smem;                         // [2*NL][512] uint4 = 114688 B
  _Float16* hx16 = (_Float16*)(smem + 114688);      // 256 f16 = 512 B
  float* red  = (float*)(smem + 115200);            // 16 floats
  float* red2 = (float*)(smem + 115264);            // 8 floats
  float* gact = (float*)(smem + 115296);            // 1024 floats -> end 119392

  const int tid = threadIdx.x;
  const int b = blockIdx.x;
  const int lane = tid & 63, wid = tid >> 6;
  const int q = wid >> 1, r = wid & 1;
  const int gA = q * 256 + r * 128 + lane;
  const int gB = gA + 64;

  uint4 wrA[NV], wrB[NV];
#pragma unroll
  for (int kb = 0; kb < NV; ++kb) {
    wrA[kb] = whp4[kb * 1024 + gA];
    wrB[kb] = whp4[kb * 1024 + gB];
  }
#pragma unroll
  for (int j = 0; j < NL; ++j) {
    wl[j * 512 + tid]        = whp4[(NV + j) * 1024 + gA];
    wl[(NL + j) * 512 + tid] = whp4[(NV + j) * 1024 + gB];
  }
  float lgA = lna_g[gA], lbA = lna_b[gA];
  float lgB = lna_g[gB], lbB = lna_b[gB];
  float lng = 0.f, lnb = 0.f, cx = 0.f;
  if (tid < HH) {
    lng = ln_g[tid]; lnb = ln_b[tid];
    if (t0 == 0) {
      hx16[tid] = (_Float16)0.f;
    } else {
      hx16[tid] = hxst[b * HH + tid]; cx = cxst[b * HH + tid];
    }
  }
  __syncthreads();

  const _Float16* xrA = xphf + b * GG + gA;
  const _Float16* xrB = xphf + b * GG + gB;
  _Float16* hsp = hs16 + (size_t)b * HH + (tid & 255);

  _Float16 xA16 = xrA[0], xB16 = xrB[0];
  for (int tl = 0; tl < ct; ++tl) {
    // lane l picks up hx[4l .. 4l+3] (pairs 2l, 2l+1); 2-way bank alias = free
    uint2 hp = *(const uint2*)(hx16 + 4 * lane);
    float accA = (float)xA16, accB = (float)xB16;
    if (tl + 1 < ct) {   // prefetch next step's xproj
      xA16 = xrA[(size_t)(tl + 1) * (BB * GG)];
      xB16 = xrB[(size_t)(tl + 1) * (BB * GG)];
    }
#pragma unroll
    for (int kb = 0; kb < NV; ++kb) {
      u32 h0 = (u32)__builtin_amdgcn_readlane((int)hp.x, 2 * kb);
      u32 h1 = (u32)__builtin_amdgcn_readlane((int)hp.y, 2 * kb);
      u32 h2 = (u32)__builtin_amdgcn_readlane((int)hp.x, 2 * kb + 1);
      u32 h3 = (u32)__builtin_amdgcn_readlane((int)hp.y, 2 * kb + 1);
      accA = fdot2(wrA[kb].x, h0, accA);
      accA = fdot2(wrA[kb].y, h1, accA);
      accA = fdot2(wrA[kb].z, h2, accA);
      accA = fdot2(wrA[kb].w, h3, accA);
      accB = fdot2(wrB[kb].x, h0, accB);
      accB = fdot2(wrB[kb].y, h1, accB);
      accB = fdot2(wrB[kb].z, h2, accB);
      accB = fdot2(wrB[kb].w, h3, accB);
    }
#pragma unroll
    for (int j = 0; j < NL; ++j) {
      const int kb = NV + j;
      u32 h0 = (u32)__builtin_amdgcn_readlane((int)hp.x, 2 * kb);
      u32 h1 = (u32)__builtin_amdgcn_readlane((int)hp.y, 2 * kb);
      u32 h2 = (u32)__builtin_amdgcn_readlane((int)hp.x, 2 * kb + 1);
      u32 h3 = (u32)__builtin_amdgcn_readlane((int)hp.y, 2 * kb + 1);
      uint4 wA = wl[j * 512 + tid];
      uint4 wB = wl[(NL + j) * 512 + tid];
      accA = fdot2(wA.x, h0, accA);
      accA = fdot2(wA.y, h1, accA);
      accA = fdot2(wA.z, h2, accA);
      accA = fdot2(wA.w, h3, accA);
      accB = fdot2(wB.x, h0, accB);
      accB = fdot2(wB.y, h1, accB);
      accB = fdot2(wB.z, h2, accB);
      accB = fdot2(wB.w, h3, accB);
    }

    // gate-block LN over 256 gates = waves {2q, 2q+1}
    float s = accA + accB, ss = accA * accA + accB * accB;
#pragma unroll
    for (int m = 1; m <= 32; m <<= 1) {
      s += __shfl_xor(s, m, 64);
      ss += __shfl_xor(ss, m, 64);
    }
    if (lane == 0) { red[wid] = s; red[8 + wid] = ss; }
    __syncthreads();                                  // B1
    float S  = red[2 * q] + red[2 * q + 1];
    float SS = red[8 + 2 * q] + red[8 + 2 * q + 1];
    float mean = S * (1.f / HH);
    float var = SS * (1.f / HH) - mean * mean;
    float rstd = rsqrtf(var + LN_EPS);
    float gnA = (accA - mean) * rstd * lgA + lbA;
    float gnB = (accB - mean) * rstd * lgB + lbB;
    float avA, avB;
    if (q == 2) { avA = fast_tanh(gnA); avB = fast_tanh(gnB); }      // wave-uniform branch
    else        { avA = fast_sigmoid(gnA); avB = fast_sigmoid(gnB); }
    gact[gA] = avA; gact[gB] = avB;
    __syncthreads();                                  // B2

    float cy = 0.f;
    if (tid < HH) {
      int h = tid;
      cy = gact[HH + h] * cx + gact[h] * gact[2 * HH + h];
      cx = cy;
      float s2 = cy, ss2 = cy * cy;
#pragma unroll
      for (int m = 1; m <= 32; m <<= 1) {
        s2 += __shfl_xor(s2, m, 64);
        ss2 += __shfl_xor(ss2, m, 64);
      }
      if (lane == 0) { red2[wid] = s2; red2[4 + wid] = ss2; }
    }
    __syncthreads();                                  // B3
    if (tid < HH) {
      int h = tid;
      float S2  = red2[0] + red2[1] + red2[2] + red2[3];
      float SS2 = red2[4] + red2[5] + red2[6] + red2[7];
      float mc = S2 * (1.f / HH);
      float vc = SS2 * (1.f / HH) - mc * mc;
      float cyn = (cy - mc) * rsqrtf(vc + LN_EPS) * lng + lnb;
      float hy = gact[3 * HH + h] * fast_tanh(cyn);
      hx16[h] = (_Float16)hy;
      hsp[(size_t)(t0 + tl) * (BB * HH)] = (_Float16)hy;
    }
    __syncthreads();                                  // B4
  }
  if (tid < HH) { hxst[b * HH + tid] = hx16[tid]; cxst[b * HH + tid] = cx; }
}

// ---------------- out GEMM: out[b][t][o] = relu(sum_h hs[t][b][h]*Wf[o][h] + bf[o])
__global__ __launch_bounds__(256) void out_gemm(
    const _Float16* __restrict__ hs16, const float* __restrict__ Wf,
    const float* __restrict__ bf, float* __restrict__ out) {
  __shared__ u32 wfl[128][64];    // pairs [kp][o], 32KB
  __shared__ u32 hsl[16][132];    // pairs [p][kp], padded
  const int tid = threadIdx.x;
  const int mbase = blockIdx.x * 16;
#pragma unroll
  for (int i = 0; i < 32; ++i) {  // 8192 pairs of Wf
    int idx = i * 256 + tid;
    int kp = idx >> 6, o = idx & 63;
    wfl[kp][o] = pkf16(Wf[o * HH + kp * 2], Wf[o * HH + kp * 2 + 1]);
  }
#pragma unroll
  for (int i = 0; i < 8; ++i) {   // 2048 pairs of hs
    int idx = i * 256 + tid;
    int p = idx >> 7, kp = idx & 127;
    hsl[p][kp] = *(const u32*)(hs16 + (size_t)(mbase + p) * HH + kp * 2);
  }
  __syncthreads();
  const int o = tid & 63, mi = tid >> 6;
  float bfo = bf[o];
#pragma unroll
  for (int mm = mi; mm < 16; mm += 4) {
    float a0 = bfo, a1 = 0.f, a2 = 0.f, a3 = 0.f;
#pragma unroll
    for (int kp = 0; kp < 128; kp += 4) {
      a0 = fdot2(wfl[kp + 0][o], hsl[mm][kp + 0], a0);
      a1 = fdot2(wfl[kp + 1][o], hsl[mm][kp + 1], a1);
      a2 = fdot2(wfl[kp + 2][o], hsl[mm][kp + 2], a2);
      a3 = fdot2(wfl[kp + 3][o], hsl[mm][kp + 3], a3);
    }
    float r = (a0 + a1) + (a2 + a3);
    int m = mbase + mm;
    out[(size_t)(m & 63) * (T_TOT * OO) + (size_t)(m >> 6) * OO + o] = fmaxf(r, 0.f);
  }
}

extern "C" void kernel_launch(void* const* d_in, const int* in_sizes, int n_in,
                              void* d_out, int out_size, void* d_ws, size_t ws_size,
                              hipStream_t stream) {
  if (n_in < 11) return;
  const float* x    = (const float*)d_in[0];
  const float* Wi   = (const float*)d_in[1];
  const float* bi   = (const float*)d_in[2];
  const float* Wh   = (const float*)d_in[3];
  const float* bh   = (const float*)d_in[4];
  const float* lnag = (const float*)d_in[5];
  const float* lnab = (const float*)d_in[6];
  const float* lng  = (const float*)d_in[7];
  const float* lnb  = (const float*)d_in[8];
  const float* Wf   = (const float*)d_in[9];
  const float* bf   = (const float*)d_in[10];
  float* out = (float*)d_out;

  char* ws = (char*)d_ws;
  uint4* whp4 = (uint4*)ws;                                  // 512 KB
  uint4* wip4 = (uint4*)(ws + (512 << 10));                  // 256 KB
  _Float16* hs16 = (_Float16*)(ws + (1 << 20));              // 32 MB
  _Float16* hxst = (_Float16*)(ws + (1 << 20) + (32 << 20)); // 32 KB
  float* cxst = (float*)(ws + (1 << 20) + (32 << 20) + (64 << 10)); // 64 KB
  const size_t xph_off = (size_t)35 << 20;
  _Float16* xph = (_Float16*)(ws + xph_off);

  size_t avail = ws_size > xph_off ? ws_size - xph_off : 0;
  int ct = T_TOT;
  while (ct > 1 && (size_t)ct * (BB * GG * 2) > avail) ct >>= 1;

  const int scan_smem = 119392;   // 114688 wl + 512 hx + 64 red + 32 red2 + 4096 gact
  (void)hipFuncSetAttribute(reinterpret_cast<const void*>(lstm_scan),
                            hipFuncAttributeMaxDynamicSharedMemorySize, scan_smem);

  prep_wh<<<128, 256, 0, stream>>>(Wh, whp4);
  prep_wi<<<64, 256, 0, stream>>>(Wi, wip4);
  for (int t0 = 0; t0 < T_TOT; t0 += ct) {
    xproj_gemm<<<dim3((ct * BB) / 16, 4), 256, 0, stream>>>(x, wip4, bi, bh, xph, t0 * BB);
    lstm_scan<<<BB, 512, scan_smem, stream>>>(whp4, xph, lnag, lnab, lng, lnb,
                                              hs16, hxst, cxst, t0, ct);
  }
  out_gemm<<<(T_TOT * BB) / 16, 256, 0, stream>>>(hs16, Wf, bf, out);
}